// Round 1
// baseline (749.980 us; speedup 1.0000x reference)
//
#include <hip/hip_runtime.h>

// Problem constants (from reference): B=2, S=2048, IN=4096, OUT=4096, RANK=8, LORA_R=16
#define M_DIM 4096   // B*S
#define IN_DIM 4096
#define OUT_DIM 4096
#define RANK 8
#define LORA_R 16
#define LORA_SCALING 1.0f   // 16.0 / LORA_R

typedef __bf16 bf16;
typedef bf16  bf16x4 __attribute__((ext_vector_type(4)));
typedef bf16  bf16x8 __attribute__((ext_vector_type(8)));
typedef float f32x4  __attribute__((ext_vector_type(4)));

// -------------------------------------------------------------------------
// Kernel 1: fold rank-8 scale factor + rank-16 LoRA into one bf16 weight.
// W_tot[o,i] = weight[o,i] * sum_k(scale_A[o,k]*g[k]*scale_B[k,i])
//            + LORA_SCALING * sum_r(lora_B[o,r]*lora_A[r,i])
// OG=8 rows per block so the scale_B / lora_A panels (384 KB) are re-read
// only 512x (L2-resident, ~6 us) instead of 4096x.
// -------------------------------------------------------------------------
#define OG 8
__global__ __launch_bounds__(256) void prep_weight(
    const float* __restrict__ weight, const float* __restrict__ scale_A,
    const float* __restrict__ scale_B, const float* __restrict__ g,
    const float* __restrict__ lora_A, const float* __restrict__ lora_B,
    bf16* __restrict__ wt)
{
    __shared__ float s_sa[OG][RANK];
    __shared__ float s_lb[OG][LORA_R];
    const int o0 = blockIdx.x * OG;
    const int t  = threadIdx.x;
    if (t < OG * RANK) {
        int r8 = t / RANK, k = t % RANK;
        s_sa[r8][k] = scale_A[(o0 + r8) * RANK + k] * g[k];
    }
    if (t < OG * LORA_R) {
        int r8 = t / LORA_R, r = t % LORA_R;
        s_lb[r8][r] = lora_B[(o0 + r8) * LORA_R + r] * LORA_SCALING;
    }
    __syncthreads();

    for (int i0 = t * 4; i0 < IN_DIM; i0 += 256 * 4) {
        f32x4 sb[RANK];
        f32x4 la[LORA_R];
#pragma unroll
        for (int k = 0; k < RANK; ++k)
            sb[k] = *(const f32x4*)(scale_B + k * IN_DIM + i0);
#pragma unroll
        for (int r = 0; r < LORA_R; ++r)
            la[r] = *(const f32x4*)(lora_A + r * IN_DIM + i0);
#pragma unroll
        for (int r8 = 0; r8 < OG; ++r8) {
            f32x4 wv = *(const f32x4*)(weight + (size_t)(o0 + r8) * IN_DIM + i0);
            f32x4 s = {0.f, 0.f, 0.f, 0.f};
#pragma unroll
            for (int k = 0; k < RANK; ++k) s += s_sa[r8][k] * sb[k];
            f32x4 l = {0.f, 0.f, 0.f, 0.f};
#pragma unroll
            for (int r = 0; r < LORA_R; ++r) l += s_lb[r8][r] * la[r];
            f32x4 res = wv * s + l;
            bf16x4 h = { (bf16)res[0], (bf16)res[1], (bf16)res[2], (bf16)res[3] };
            *(bf16x4*)(wt + (size_t)(o0 + r8) * IN_DIM + i0) = h;
        }
    }
}

// -------------------------------------------------------------------------
// Kernel 2: cast x (fp32) -> bf16, vectorized float4 -> bf16x4.
// -------------------------------------------------------------------------
__global__ __launch_bounds__(256) void cast_x(
    const float* __restrict__ x, bf16* __restrict__ xb, int n4)
{
    int idx    = blockIdx.x * blockDim.x + threadIdx.x;
    int stride = gridDim.x * blockDim.x;
    for (int i = idx; i < n4; i += stride) {
        f32x4 v = *(const f32x4*)(x + (size_t)i * 4);
        bf16x4 h = { (bf16)v[0], (bf16)v[1], (bf16)v[2], (bf16)v[3] };
        *(bf16x4*)(xb + (size_t)i * 4) = h;
    }
}

// -------------------------------------------------------------------------
// Kernel 3: bf16 GEMM, C[m,n] = sum_k A[m,k] * Bw[n,k]  (B^T layout).
// m97 structure: 128x128 tile, BK=32, 4 waves (2x2), each wave 4x4 tiles of
// mfma_f32_16x16x32_bf16; staging via global_load_lds width=16 (direct-to-LDS
// DMA, wave-uniform base + lane*16 => LDS must be unpadded/linear in tid).
// -------------------------------------------------------------------------
#define BM 128
#define BN 128
#define BK 32

__device__ __forceinline__ void gload_lds16(const bf16* g, bf16* l) {
    __builtin_amdgcn_global_load_lds(
        (const __attribute__((address_space(1))) void*)g,
        (__attribute__((address_space(3))) void*)l,
        16, 0, 0);
}

__global__ __launch_bounds__(256) void gemm_bt(
    const bf16* __restrict__ A,   // [M_DIM, IN_DIM] row-major bf16
    const bf16* __restrict__ Bw,  // [OUT_DIM, IN_DIM] row-major bf16
    float* __restrict__ C)        // [M_DIM, OUT_DIM] row-major fp32
{
    __shared__ __align__(16) bf16 sA[BM * BK];  // [128][32], row stride 64 B
    __shared__ __align__(16) bf16 sB[BN * BK];

    const int t    = threadIdx.x;
    const int w    = t >> 6;     // wave id 0..3
    const int lane = t & 63;
    const int m0   = blockIdx.x * BM;
    const int n0   = blockIdx.y * BN;
    const int wm   = (w >> 1) * 64;  // wave row offset in tile
    const int wn   = (w & 1) * 64;   // wave col offset in tile

    // Staging: thread t's 16 B lands at LDS byte t*16 (wave base + lane*16).
    // Byte t*16 => tile row t/4, col-bytes (t&3)*16 => bf16 col (t&3)*8.
    const int srow = t >> 2;        // 0..63 (issue 0), +64 for issue 1
    const int scol = (t & 3) * 8;   // bf16 col within BK
    const bf16* gA0 = A  + (size_t)(m0 + srow)      * IN_DIM + scol;
    const bf16* gA1 = A  + (size_t)(m0 + 64 + srow) * IN_DIM + scol;
    const bf16* gB0 = Bw + (size_t)(n0 + srow)      * IN_DIM + scol;
    const bf16* gB1 = Bw + (size_t)(n0 + 64 + srow) * IN_DIM + scol;
    bf16* lA0 = &sA[w * 512];          // wave-uniform LDS bases (bf16 elems)
    bf16* lA1 = &sA[2048 + w * 512];
    bf16* lB0 = &sB[w * 512];
    bf16* lB1 = &sB[2048 + w * 512];

    f32x4 acc[4][4] = {};

    const int lm = lane & 15;   // A: m, B: n within 16
    const int lq = lane >> 4;   // k-quad: k = lq*8 + j

    for (int k0 = 0; k0 < IN_DIM; k0 += BK) {
        __syncthreads();  // previous iter's ds_reads done before overwrite
        gload_lds16(gA0 + k0, lA0);
        gload_lds16(gA1 + k0, lA1);
        gload_lds16(gB0 + k0, lB0);
        gload_lds16(gB1 + k0, lB1);
        __syncthreads();  // drains vmcnt: staged tiles visible

        bf16x8 af[4], bfr[4];
#pragma unroll
        for (int tm = 0; tm < 4; ++tm)
            af[tm] = *(const bf16x8*)&sA[(wm + tm * 16 + lm) * BK + lq * 8];
#pragma unroll
        for (int tn = 0; tn < 4; ++tn)
            bfr[tn] = *(const bf16x8*)&sB[(wn + tn * 16 + lm) * BK + lq * 8];
#pragma unroll
        for (int tm = 0; tm < 4; ++tm)
#pragma unroll
            for (int tn = 0; tn < 4; ++tn)
                acc[tm][tn] = __builtin_amdgcn_mfma_f32_16x16x32_bf16(
                    af[tm], bfr[tn], acc[tm][tn], 0, 0, 0);
    }

    // Epilogue. C/D layout (m89/m91-verified): col = lane&15, row = (lane>>4)*4 + reg.
    const int ccol = lane & 15;
    const int crow = (lane >> 4) * 4;
#pragma unroll
    for (int tm = 0; tm < 4; ++tm)
#pragma unroll
        for (int tn = 0; tn < 4; ++tn) {
            float* cp = C + (size_t)(m0 + wm + tm * 16 + crow) * OUT_DIM
                          + (n0 + wn + tn * 16 + ccol);
#pragma unroll
            for (int j = 0; j < 4; ++j)
                cp[(size_t)j * OUT_DIM] = acc[tm][tn][j];
        }
}

// -------------------------------------------------------------------------
extern "C" void kernel_launch(void* const* d_in, const int* in_sizes, int n_in,
                              void* d_out, int out_size, void* d_ws, size_t ws_size,
                              hipStream_t stream) {
    (void)in_sizes; (void)n_in; (void)out_size; (void)ws_size;
    const float* x        = (const float*)d_in[0];
    const float* weight   = (const float*)d_in[1];
    const float* scale_A  = (const float*)d_in[2];
    const float* scale_B  = (const float*)d_in[3];
    const float* g        = (const float*)d_in[4];
    const float* lora_A   = (const float*)d_in[5];
    const float* lora_B   = (const float*)d_in[6];
    float* out = (float*)d_out;

    bf16* xb = (bf16*)d_ws;                                             // 32 MiB
    bf16* wt = (bf16*)((char*)d_ws + (size_t)M_DIM * IN_DIM * sizeof(bf16));  // 32 MiB

    prep_weight<<<OUT_DIM / OG, 256, 0, stream>>>(weight, scale_A, scale_B, g,
                                                  lora_A, lora_B, wt);
    cast_x<<<2048, 256, 0, stream>>>(x, xb, (M_DIM * IN_DIM) / 4);

    dim3 grid(M_DIM / BM, OUT_DIM / BN);  // 32 x 32 = 1024 blocks, 4/CU
    gemm_bt<<<grid, 256, 0, stream>>>(xb, wt, out);
}